// Round 1
// baseline (1207.500 us; speedup 1.0000x reference)
//
#include <hip/hip_runtime.h>
#include <math.h>

#define D 128
#define HEADS 8
#define DH 16
#define SCALE 0.25f

// ---------------------------------------------------------------------------
// edge_index dtype detection: if the buffer is int64 (little-endian), the odd
// int32 words are the high halves == 0 for all values in [0, N). If int32,
// odd words are random node ids (~all nonzero). flag[0] = 1 if int64.
__global__ void detect_i64(const int* __restrict__ ei, int* __restrict__ flag) {
    __shared__ int cnt;
    if (threadIdx.x == 0) cnt = 0;
    __syncthreads();
    int v = ei[2 * threadIdx.x + 1];   // indices 1..2047 < 2E, safe both ways
    if (v != 0) atomicAdd(&cnt, 1);
    __syncthreads();
    if (threadIdx.x == 0) flag[0] = (cnt == 0) ? 1 : 0;
}

__global__ void zero_ints(int* __restrict__ p, int n) {
    int i = blockIdx.x * blockDim.x + threadIdx.x;
    if (i < n) p[i] = 0;
}

__global__ void count_deg(const int* __restrict__ ei, int E,
                          const int* __restrict__ flag, int* __restrict__ deg) {
    int e = blockIdx.x * blockDim.x + threadIdx.x;
    if (e >= E) return;
    int is64 = flag[0];
    int d = is64 ? ei[2 * E + 2 * e] : ei[E + e];
    atomicAdd(&deg[d], 1);
}

// single-block exclusive scan over deg[0..Nn) -> row_ptr[0..Nn], cursor copy
__global__ __launch_bounds__(1024) void scan_deg(const int* __restrict__ deg,
                                                 int* __restrict__ row_ptr,
                                                 int* __restrict__ cursor, int Nn) {
    __shared__ int buf[1024];
    int tid = threadIdx.x;
    int base = 0;
    for (int start = 0; start < Nn; start += 1024) {
        int i = start + tid;
        int v = (i < Nn) ? deg[i] : 0;
        buf[tid] = v;
        __syncthreads();
        for (int off = 1; off < 1024; off <<= 1) {
            int t = (tid >= off) ? buf[tid - off] : 0;
            __syncthreads();
            buf[tid] += t;
            __syncthreads();
        }
        int excl = buf[tid] - v;
        if (i < Nn) { row_ptr[i] = base + excl; cursor[i] = base + excl; }
        int total = buf[1023];
        __syncthreads();
        base += total;
    }
    if (tid == 0) row_ptr[Nn] = base;
}

__global__ void scatter_edges(const int* __restrict__ ei, int E,
                              const int* __restrict__ flag,
                              int* __restrict__ cursor, int* __restrict__ srcs) {
    int e = blockIdx.x * blockDim.x + threadIdx.x;
    if (e >= E) return;
    int is64 = flag[0];
    int s = is64 ? ei[2 * e]         : ei[e];
    int d = is64 ? ei[2 * E + 2 * e] : ei[E + e];
    int pos = atomicAdd(&cursor[d], 1);
    srcs[pos] = s;
}

// ---------------------------------------------------------------------------
// C[N,128] = A[N,128] @ W[128,128] + b   (fp32, BM=64, BK=32 W staging)
__global__ __launch_bounds__(256) void gemm_xw(const float* __restrict__ A,
                                               const float* __restrict__ W,
                                               const float* __restrict__ bias,
                                               float* __restrict__ C, int Nrows) {
    __shared__ float As[64][129];   // +1 pad: conflict-free column reads
    __shared__ float Ws[32][128];
    const int tid = threadIdx.x;
    const int tx = tid & 15, ty = tid >> 4;
    const int rowBase = blockIdx.x * 64;

    {   // load A tile 64x128 (float4), zero-pad rows >= Nrows
        int r = tid >> 5;
        int c4 = (tid & 31) << 2;
        #pragma unroll
        for (int it = 0; it < 8; ++it) {
            int rr = r + it * 8;
            int grow = rowBase + rr;
            float4 v = make_float4(0.f, 0.f, 0.f, 0.f);
            if (grow < Nrows) v = *(const float4*)(A + (size_t)grow * D + c4);
            As[rr][c4 + 0] = v.x; As[rr][c4 + 1] = v.y;
            As[rr][c4 + 2] = v.z; As[rr][c4 + 3] = v.w;
        }
    }

    float acc[4][8];
    #pragma unroll
    for (int i = 0; i < 4; i++)
        #pragma unroll
        for (int j = 0; j < 8; j++) acc[i][j] = 0.f;

    for (int kb = 0; kb < 4; kb++) {
        __syncthreads();
        {   // stage W rows kb*32..kb*32+31
            int r = tid >> 5;
            int c4 = (tid & 31) << 2;
            #pragma unroll
            for (int it = 0; it < 4; ++it) {
                int rr = r + it * 8;
                float4 wv = *(const float4*)(W + (size_t)(kb * 32 + rr) * D + c4);
                *(float4*)(&Ws[rr][c4]) = wv;
            }
        }
        __syncthreads();
        #pragma unroll
        for (int kk = 0; kk < 32; kk++) {
            float av[4];
            #pragma unroll
            for (int i = 0; i < 4; i++) av[i] = As[ty * 4 + i][kb * 32 + kk];
            float4 w0 = *(const float4*)(&Ws[kk][tx * 4]);
            float4 w1 = *(const float4*)(&Ws[kk][64 + tx * 4]);
            float wv[8] = {w0.x, w0.y, w0.z, w0.w, w1.x, w1.y, w1.z, w1.w};
            #pragma unroll
            for (int i = 0; i < 4; i++)
                #pragma unroll
                for (int j = 0; j < 8; j++) acc[i][j] += av[i] * wv[j];
        }
    }

    float4 b0 = *(const float4*)(bias + tx * 4);
    float4 b1 = *(const float4*)(bias + 64 + tx * 4);
    float bb[8] = {b0.x, b0.y, b0.z, b0.w, b1.x, b1.y, b1.z, b1.w};
    #pragma unroll
    for (int i = 0; i < 4; i++) {
        int grow = rowBase + ty * 4 + i;
        if (grow < Nrows) {
            float4 o0 = make_float4(acc[i][0] + bb[0], acc[i][1] + bb[1],
                                    acc[i][2] + bb[2], acc[i][3] + bb[3]);
            float4 o1 = make_float4(acc[i][4] + bb[4], acc[i][5] + bb[5],
                                    acc[i][6] + bb[6], acc[i][7] + bb[7]);
            *(float4*)(C + (size_t)grow * D + tx * 4) = o0;
            *(float4*)(C + (size_t)grow * D + 64 + tx * 4) = o1;
        }
    }
}

// ---------------------------------------------------------------------------
// One wave per dst node: online-softmax attention aggregation.
// lane l holds dims l (head l/16) and l+64 (head 4 + l/16).
// out[n] = maybe_prelu(agg[n] + skip[n] (+ resid[n]))
__global__ __launch_bounds__(256) void attn_agg(
    const float* __restrict__ q, const float* __restrict__ k,
    const float* __restrict__ v, const int* __restrict__ row_ptr,
    const int* __restrict__ srcs, const float* __restrict__ skip,
    const float* __restrict__ resid, const float* __restrict__ a_ptr,
    float* __restrict__ out, int Nn) {
    int n = blockIdx.x * 4 + (threadIdx.x >> 6);
    if (n >= Nn) return;
    int lane = threadIdx.x & 63;
    const float a = a_ptr[0];

    float q_lo = q[(size_t)n * D + lane];
    float q_hi = q[(size_t)n * D + 64 + lane];
    float m_lo = -INFINITY, m_hi = -INFINITY;
    float s_lo = 0.f, s_hi = 0.f, acc_lo = 0.f, acc_hi = 0.f;

    int beg = row_ptr[n], end = row_ptr[n + 1];
    for (int j = beg; j < end; ++j) {
        int s = srcs[j];
        const float* kr = k + (size_t)s * D;
        const float* vr = v + (size_t)s * D;
        float p_lo = q_lo * kr[lane];
        float p_hi = q_hi * kr[64 + lane];
        #pragma unroll
        for (int off = 1; off < 16; off <<= 1) {
            p_lo += __shfl_xor(p_lo, off);
            p_hi += __shfl_xor(p_hi, off);
        }
        float sc_lo = p_lo * SCALE;
        float sc_hi = p_hi * SCALE;
        float vv_lo = vr[lane];
        float vv_hi = vr[64 + lane];

        float nm = fmaxf(m_lo, sc_lo);
        float corr = __expf(m_lo - nm);   // first iter: exp(-inf) = 0
        float w = __expf(sc_lo - nm);
        acc_lo = acc_lo * corr + w * vv_lo;
        s_lo = s_lo * corr + w;
        m_lo = nm;

        nm = fmaxf(m_hi, sc_hi);
        corr = __expf(m_hi - nm);
        w = __expf(sc_hi - nm);
        acc_hi = acc_hi * corr + w * vv_hi;
        s_hi = s_hi * corr + w;
        m_hi = nm;
    }

    float agg_lo = (end > beg) ? acc_lo / s_lo : 0.f;
    float agg_hi = (end > beg) ? acc_hi / s_hi : 0.f;
    float o_lo = agg_lo + skip[(size_t)n * D + lane];
    float o_hi = agg_hi + skip[(size_t)n * D + 64 + lane];
    if (resid) {
        o_lo += resid[(size_t)n * D + lane];
        o_hi += resid[(size_t)n * D + 64 + lane];
    }
    o_lo = (o_lo >= 0.f) ? o_lo : a * o_lo;
    o_hi = (o_hi >= 0.f) ? o_hi : a * o_hi;
    out[(size_t)n * D + lane] = o_lo;
    out[(size_t)n * D + 64 + lane] = o_hi;
}

// ---------------------------------------------------------------------------
extern "C" void kernel_launch(void* const* d_in, const int* in_sizes, int n_in,
                              void* d_out, int out_size, void* d_ws, size_t ws_size,
                              hipStream_t stream) {
    const float* x  = (const float*)d_in[0];
    const int*   ei = (const int*)d_in[1];
    const float* a  = (const float*)d_in[2];
    // dict order: Wq1,bq1, Wk1,bk1, Wv1,bv1, Ws1,bs1, Wq2,bq2, Wk2,bk2, Wv2,bv2, Ws2,bs2
    const float* Wq1 = (const float*)d_in[3];  const float* bq1 = (const float*)d_in[4];
    const float* Wk1 = (const float*)d_in[5];  const float* bk1 = (const float*)d_in[6];
    const float* Wv1 = (const float*)d_in[7];  const float* bv1 = (const float*)d_in[8];
    const float* Ws1 = (const float*)d_in[9];  const float* bs1 = (const float*)d_in[10];
    const float* Wq2 = (const float*)d_in[11]; const float* bq2 = (const float*)d_in[12];
    const float* Wk2 = (const float*)d_in[13]; const float* bk2 = (const float*)d_in[14];
    const float* Wv2 = (const float*)d_in[15]; const float* bv2 = (const float*)d_in[16];
    const float* Ws2 = (const float*)d_in[17]; const float* bs2 = (const float*)d_in[18];

    const int N = in_sizes[0] / D;        // 100000
    const int E = in_sizes[1] / 2;        // 1000000
    const size_t NF = (size_t)N * D;

    float* q  = (float*)d_ws;
    float* kk = q + NF;
    float* vv = kk + NF;
    float* h1 = vv + NF;
    int* ibase   = (int*)(h1 + NF);
    int* flag    = ibase;
    int* deg     = ibase + 16;            // keep 16B alignment headroom
    int* row_ptr = deg + N;
    int* cursor  = row_ptr + N + 1;
    int* srcs    = cursor + N;
    float* skip  = (float*)d_out;         // skip tensors staged through d_out
    float* out   = (float*)d_out;

    const int TB = 256;
    int gN = (N + TB - 1) / TB;
    int gE = (E + TB - 1) / TB;
    int gGemm = (N + 63) / 64;
    int gAttn = (N + 3) / 4;

    // ---- CSR build (edges identical for both layers) ----
    hipLaunchKernelGGL(detect_i64, dim3(1), dim3(1024), 0, stream, ei, flag);
    hipLaunchKernelGGL(zero_ints, dim3(gN), dim3(TB), 0, stream, deg, N);
    hipLaunchKernelGGL(count_deg, dim3(gE), dim3(TB), 0, stream, ei, E, flag, deg);
    hipLaunchKernelGGL(scan_deg, dim3(1), dim3(1024), 0, stream, deg, row_ptr, cursor, N);
    hipLaunchKernelGGL(scatter_edges, dim3(gE), dim3(TB), 0, stream, ei, E, flag, cursor, srcs);

    // ---- layer 1 ----
    hipLaunchKernelGGL(gemm_xw, dim3(gGemm), dim3(TB), 0, stream, x, Wq1, bq1, q, N);
    hipLaunchKernelGGL(gemm_xw, dim3(gGemm), dim3(TB), 0, stream, x, Wk1, bk1, kk, N);
    hipLaunchKernelGGL(gemm_xw, dim3(gGemm), dim3(TB), 0, stream, x, Wv1, bv1, vv, N);
    hipLaunchKernelGGL(gemm_xw, dim3(gGemm), dim3(TB), 0, stream, x, Ws1, bs1, skip, N);
    hipLaunchKernelGGL(attn_agg, dim3(gAttn), dim3(TB), 0, stream,
                       q, kk, vv, row_ptr, srcs, skip, (const float*)nullptr, a, h1, N);

    // ---- layer 2 ----
    hipLaunchKernelGGL(gemm_xw, dim3(gGemm), dim3(TB), 0, stream, h1, Wq2, bq2, q, N);
    hipLaunchKernelGGL(gemm_xw, dim3(gGemm), dim3(TB), 0, stream, h1, Wk2, bk2, kk, N);
    hipLaunchKernelGGL(gemm_xw, dim3(gGemm), dim3(TB), 0, stream, h1, Wv2, bv2, vv, N);
    hipLaunchKernelGGL(gemm_xw, dim3(gGemm), dim3(TB), 0, stream, h1, Ws2, bs2, skip, N);
    hipLaunchKernelGGL(attn_agg, dim3(gAttn), dim3(TB), 0, stream,
                       q, kk, vv, row_ptr, srcs, skip, x, a, out, N);
}

// Round 2
// 747.993 us; speedup vs baseline: 1.6143x; 1.6143x over previous
//
#include <hip/hip_runtime.h>
#include <hip/hip_bf16.h>
#include <math.h>

#define D 128
#define SCALE 0.25f

typedef __attribute__((ext_vector_type(8))) short bf16x8;
typedef __attribute__((ext_vector_type(4))) float f32x4;

// ---------------------------------------------------------------------------
// edge_index dtype detection (int64 vs int32) — see round 0 notes.
__global__ void detect_i64(const int* __restrict__ ei, int* __restrict__ flag) {
    __shared__ int cnt;
    if (threadIdx.x == 0) cnt = 0;
    __syncthreads();
    int v = ei[2 * threadIdx.x + 1];
    if (v != 0) atomicAdd(&cnt, 1);
    __syncthreads();
    if (threadIdx.x == 0) flag[0] = (cnt == 0) ? 1 : 0;
}

__global__ void zero_ints(int* __restrict__ p, int n) {
    int i = blockIdx.x * blockDim.x + threadIdx.x;
    if (i < n) p[i] = 0;
}

__global__ void count_deg(const int* __restrict__ ei, int E,
                          const int* __restrict__ flag, int* __restrict__ deg) {
    int e = blockIdx.x * blockDim.x + threadIdx.x;
    if (e >= E) return;
    int is64 = flag[0];
    int d = is64 ? ei[2 * E + 2 * e] : ei[E + e];
    atomicAdd(&deg[d], 1);
}

// ---- 3-phase device-wide exclusive scan (replaces single-block serial scan)
__global__ __launch_bounds__(1024) void scan_blocks(const int* __restrict__ deg,
                                                    int* __restrict__ row_ptr,
                                                    int* __restrict__ bsum, int Nn) {
    __shared__ int buf[1024];
    int tid = threadIdx.x;
    int i = blockIdx.x * 1024 + tid;
    int v = (i < Nn) ? deg[i] : 0;
    buf[tid] = v;
    __syncthreads();
    for (int off = 1; off < 1024; off <<= 1) {
        int t = (tid >= off) ? buf[tid - off] : 0;
        __syncthreads();
        buf[tid] += t;
        __syncthreads();
    }
    if (i < Nn) row_ptr[i] = buf[tid] - v;   // block-local exclusive
    if (tid == 1023) bsum[blockIdx.x] = buf[1023];
}

__global__ __launch_bounds__(1024) void scan_bsum(int* __restrict__ bsum,
                                                  int* __restrict__ boff,
                                                  int NB, int* __restrict__ row_ptr, int Nn) {
    __shared__ int buf[1024];
    int tid = threadIdx.x;
    int v = (tid < NB) ? bsum[tid] : 0;
    buf[tid] = v;
    __syncthreads();
    for (int off = 1; off < 1024; off <<= 1) {
        int t = (tid >= off) ? buf[tid - off] : 0;
        __syncthreads();
        buf[tid] += t;
        __syncthreads();
    }
    if (tid < NB) boff[tid] = buf[tid] - v;
    if (tid == 0) row_ptr[Nn] = buf[NB - 1];  // grand total
}

__global__ void add_offsets(int* __restrict__ row_ptr, int* __restrict__ cursor,
                            const int* __restrict__ boff, int Nn) {
    int i = blockIdx.x * blockDim.x + threadIdx.x;
    if (i < Nn) {
        int r = row_ptr[i] + boff[i >> 10];
        row_ptr[i] = r;
        cursor[i] = r;
    }
}

__global__ void scatter_edges(const int* __restrict__ ei, int E,
                              const int* __restrict__ flag,
                              int* __restrict__ cursor, int* __restrict__ srcs) {
    int e = blockIdx.x * blockDim.x + threadIdx.x;
    if (e >= E) return;
    int is64 = flag[0];
    int s = is64 ? ei[2 * e]         : ei[e];
    int d = is64 ? ei[2 * E + 2 * e] : ei[E + e];
    int pos = atomicAdd(&cursor[d], 1);
    srcs[pos] = s;
}

// ---------------------------------------------------------------------------
// Pack 8 fp32 [128,128] weight matrices (k-major) into bf16 col-major
// Wt[(layer*512 + cb*128 + col)*128 + k]
struct PackArgs { const float* w[8]; };

__global__ __launch_bounds__(256) void pack_w(PackArgs pa, __hip_bfloat16* __restrict__ out) {
    int b = blockIdx.x;                 // matrix index 0..7
    const float* W = pa.w[b];
    __hip_bfloat16* dst = out + (size_t)b * 128 * 128;
    for (int idx = threadIdx.x; idx < 128 * 128; idx += 256) {
        int c = idx & 127, k = idx >> 7;           // coalesced reads over c
        dst[(size_t)c * 128 + k] = __float2bfloat16(W[(size_t)k * 128 + c]);
    }
}

__global__ void f32_to_bf16(const float* __restrict__ in, __hip_bfloat16* __restrict__ out, int n4) {
    int i = blockIdx.x * blockDim.x + threadIdx.x;
    if (i >= n4) return;
    float4 v = ((const float4*)in)[i];
    __hip_bfloat162 a, b;
    a.x = __float2bfloat16(v.x); a.y = __float2bfloat16(v.y);
    b.x = __float2bfloat16(v.z); b.y = __float2bfloat16(v.w);
    ((__hip_bfloat162*)out)[2 * i]     = a;
    ((__hip_bfloat162*)out)[2 * i + 1] = b;
}

// ---------------------------------------------------------------------------
// Fused 4-way GEMM: [M,128]bf16 @ Wt[512,128]bf16 -> q(f32) | k(bf16) | v(bf16) | skip(f32)
// blockIdx.y = output column block cb. 64 rows x 128 cols per block, 4 waves.
// Wave (wr,wc): rows wr*32..+32, cols wc*64..+64 -> 2x4 tiles of 16x16, K=128.
// No LDS: fragments loaded straight from global (A/W are L1/L2-resident).
__global__ __launch_bounds__(256) void gemm_mfma(
    const __hip_bfloat16* __restrict__ A,   // [M,128]
    const __hip_bfloat16* __restrict__ Wt,  // [512,128] (col,k)
    const float* __restrict__ bq, const float* __restrict__ bk,
    const float* __restrict__ bv, const float* __restrict__ bs,
    float* __restrict__ qout, __hip_bfloat16* __restrict__ kout,
    __hip_bfloat16* __restrict__ vout, float* __restrict__ sout, int M)
{
    const int tid = threadIdx.x;
    const int w = tid >> 6, lane = tid & 63;
    const int wr = w >> 1, wc = w & 1;
    const int cb = blockIdx.y;
    const int rowBase = blockIdx.x * 64 + wr * 32;
    const int l16 = lane & 15;
    const int quad = lane >> 4;

    f32x4 acc[2][4];
    #pragma unroll
    for (int i = 0; i < 2; i++)
        #pragma unroll
        for (int j = 0; j < 4; j++) acc[i][j] = (f32x4){0.f, 0.f, 0.f, 0.f};

    const __hip_bfloat16* Wblk = Wt + (size_t)cb * 128 * 128;

    #pragma unroll
    for (int kb = 0; kb < 4; ++kb) {
        const int k0 = kb * 32 + quad * 8;
        bf16x8 afrag[2];
        #pragma unroll
        for (int i = 0; i < 2; ++i) {
            int r = rowBase + i * 16 + l16;
            if (r >= M) r = M - 1;               // clamp: row r of D only depends on row r of A
            afrag[i] = *(const bf16x8*)(A + (size_t)r * D + k0);
        }
        #pragma unroll
        for (int j = 0; j < 4; ++j) {
            int c = wc * 64 + j * 16 + l16;
            bf16x8 bfrag = *(const bf16x8*)(Wblk + (size_t)c * D + k0);
            #pragma unroll
            for (int i = 0; i < 2; ++i)
                acc[i][j] = __builtin_amdgcn_mfma_f32_16x16x32_bf16(afrag[i], bfrag, acc[i][j], 0, 0, 0);
        }
    }

    // epilogue: C/D layout col=lane&15, row=quad*4+reg  [m89-verified]
    #pragma unroll
    for (int i = 0; i < 2; ++i) {
        #pragma unroll
        for (int r = 0; r < 4; ++r) {
            int grow = rowBase + i * 16 + quad * 4 + r;
            if (grow >= M) continue;
            #pragma unroll
            for (int j = 0; j < 4; ++j) {
                int col = wc * 64 + j * 16 + l16;
                float val = acc[i][j][r];
                size_t oidx = (size_t)grow * D + col;
                if (cb == 0)      qout[oidx] = val + bq[col];
                else if (cb == 1) kout[oidx] = __float2bfloat16(val + bk[col]);
                else if (cb == 2) vout[oidx] = __float2bfloat16(val + bv[col]);
                else              sout[oidx] = val + bs[col];
            }
        }
    }
}

// ---------------------------------------------------------------------------
// One wave per dst node, online softmax. Lane l holds dims {2l, 2l+1},
// head h = l>>3; per-head dot reduced over 8 lanes (xor 1,2,4).
__device__ inline void store_pair(float* base, int idx, float o0, float o1) {
    ((float2*)base)[idx] = make_float2(o0, o1);
}
__device__ inline void store_pair(__hip_bfloat16* base, int idx, float o0, float o1) {
    __hip_bfloat162 hv;
    hv.x = __float2bfloat16(o0);
    hv.y = __float2bfloat16(o1);
    ((__hip_bfloat162*)base)[idx] = hv;
}

template <typename OutT>
__global__ __launch_bounds__(256) void attn_agg(
    const float* __restrict__ q, const __hip_bfloat16* __restrict__ k,
    const __hip_bfloat16* __restrict__ v, const int* __restrict__ row_ptr,
    const int* __restrict__ srcs, const float* __restrict__ skip,
    const float* __restrict__ resid, const float* __restrict__ a_ptr,
    OutT* __restrict__ out, int Nn) {
    int n = blockIdx.x * 4 + (threadIdx.x >> 6);
    if (n >= Nn) return;
    int lane = threadIdx.x & 63;
    const float a = a_ptr[0];

    float2 qv = ((const float2*)(q + (size_t)n * D))[lane];
    float m = -INFINITY, s = 0.f, a0 = 0.f, a1 = 0.f;

    int beg = row_ptr[n], end = row_ptr[n + 1];
    for (int j = beg; j < end; ++j) {
        int src = srcs[j];
        __hip_bfloat162 kp = ((const __hip_bfloat162*)(k + (size_t)src * D))[lane];
        __hip_bfloat162 vp = ((const __hip_bfloat162*)(v + (size_t)src * D))[lane];
        float p = qv.x * __bfloat162float(kp.x) + qv.y * __bfloat162float(kp.y);
        p += __shfl_xor(p, 1);
        p += __shfl_xor(p, 2);
        p += __shfl_xor(p, 4);
        float sc = p * SCALE;
        float v0 = __bfloat162float(vp.x);
        float v1 = __bfloat162float(vp.y);

        float nm = fmaxf(m, sc);
        float corr = __expf(m - nm);     // first iter: exp(-inf)=0
        float wgt = __expf(sc - nm);
        a0 = a0 * corr + wgt * v0;
        a1 = a1 * corr + wgt * v1;
        s = s * corr + wgt;
        m = nm;
    }

    float inv = (end > beg) ? 1.f / s : 0.f;
    float2 sk = ((const float2*)(skip + (size_t)n * D))[lane];
    float o0 = a0 * inv + sk.x;
    float o1 = a1 * inv + sk.y;
    if (resid) {
        float2 rs = ((const float2*)(resid + (size_t)n * D))[lane];
        o0 += rs.x; o1 += rs.y;
    }
    o0 = (o0 >= 0.f) ? o0 : a * o0;
    o1 = (o1 >= 0.f) ? o1 : a * o1;
    store_pair(out, n * (D / 2) + lane, o0, o1);
}

// ---------------------------------------------------------------------------
extern "C" void kernel_launch(void* const* d_in, const int* in_sizes, int n_in,
                              void* d_out, int out_size, void* d_ws, size_t ws_size,
                              hipStream_t stream) {
    const float* x  = (const float*)d_in[0];
    const int*   ei = (const int*)d_in[1];
    const float* a  = (const float*)d_in[2];
    const float* Wq1 = (const float*)d_in[3];  const float* bq1 = (const float*)d_in[4];
    const float* Wk1 = (const float*)d_in[5];  const float* bk1 = (const float*)d_in[6];
    const float* Wv1 = (const float*)d_in[7];  const float* bv1 = (const float*)d_in[8];
    const float* Ws1 = (const float*)d_in[9];  const float* bs1 = (const float*)d_in[10];
    const float* Wq2 = (const float*)d_in[11]; const float* bq2 = (const float*)d_in[12];
    const float* Wk2 = (const float*)d_in[13]; const float* bk2 = (const float*)d_in[14];
    const float* Wv2 = (const float*)d_in[15]; const float* bv2 = (const float*)d_in[16];
    const float* Ws2 = (const float*)d_in[17]; const float* bs2 = (const float*)d_in[18];

    const int N = in_sizes[0] / D;        // 100000
    const int E = in_sizes[1] / 2;        // 1000000 (element count, dtype-independent)
    const size_t NF = (size_t)N * D;

    char* wp = (char*)d_ws;
    __hip_bfloat16* xb  = (__hip_bfloat16*)wp; wp += NF * 2;
    __hip_bfloat16* h1b = (__hip_bfloat16*)wp; wp += NF * 2;
    float* q            = (float*)wp;          wp += NF * 4;
    __hip_bfloat16* kb  = (__hip_bfloat16*)wp; wp += NF * 2;
    __hip_bfloat16* vb  = (__hip_bfloat16*)wp; wp += NF * 2;
    __hip_bfloat16* WtP = (__hip_bfloat16*)wp; wp += 2 * 512 * 128 * 2;
    int* flag    = (int*)wp;  wp += 64;
    int* deg     = (int*)wp;  wp += (size_t)N * 4;
    int* row_ptr = (int*)wp;  wp += (size_t)(N + 64) * 4;
    int* cursor  = (int*)wp;  wp += (size_t)N * 4;
    int* bsum    = (int*)wp;  wp += 1024 * 4;
    int* boff    = (int*)wp;  wp += 1024 * 4;
    int* srcs    = (int*)wp;  wp += (size_t)E * 4;
    float* skip  = (float*)d_out;     // skip staged through d_out
    float* out   = (float*)d_out;

    const int TB = 256;
    int gN = (N + TB - 1) / TB;
    int gE = (E + TB - 1) / TB;
    int NB = (N + 1023) / 1024;
    int gGemm = (N + 63) / 64;
    int gAttn = (N + 3) / 4;
    int gCvt  = ((int)(NF / 4) + TB - 1) / TB;

    // ---- CSR build ----
    hipLaunchKernelGGL(detect_i64, dim3(1), dim3(1024), 0, stream, ei, flag);
    hipLaunchKernelGGL(zero_ints, dim3(gN), dim3(TB), 0, stream, deg, N);
    hipLaunchKernelGGL(count_deg, dim3(gE), dim3(TB), 0, stream, ei, E, flag, deg);
    hipLaunchKernelGGL(scan_blocks, dim3(NB), dim3(1024), 0, stream, deg, row_ptr, bsum, N);
    hipLaunchKernelGGL(scan_bsum, dim3(1), dim3(1024), 0, stream, bsum, boff, NB, row_ptr, N);
    hipLaunchKernelGGL(add_offsets, dim3(gN), dim3(TB), 0, stream, row_ptr, cursor, boff, N);
    hipLaunchKernelGGL(scatter_edges, dim3(gE), dim3(TB), 0, stream, ei, E, flag, cursor, srcs);

    // ---- weight pack + input convert ----
    PackArgs pa;
    pa.w[0] = Wq1; pa.w[1] = Wk1; pa.w[2] = Wv1; pa.w[3] = Ws1;
    pa.w[4] = Wq2; pa.w[5] = Wk2; pa.w[6] = Wv2; pa.w[7] = Ws2;
    hipLaunchKernelGGL(pack_w, dim3(8), dim3(TB), 0, stream, pa, WtP);
    hipLaunchKernelGGL(f32_to_bf16, dim3(gCvt), dim3(TB), 0, stream, x, xb, (int)(NF / 4));

    // ---- layer 1 ----
    hipLaunchKernelGGL(gemm_mfma, dim3(gGemm, 4), dim3(TB), 0, stream,
                       xb, WtP, bq1, bk1, bv1, bs1, q, kb, vb, skip, N);
    hipLaunchKernelGGL(attn_agg<__hip_bfloat16>, dim3(gAttn), dim3(TB), 0, stream,
                       q, kb, vb, row_ptr, srcs, skip, (const float*)nullptr, a, h1b, N);

    // ---- layer 2 ----
    hipLaunchKernelGGL(gemm_mfma, dim3(gGemm, 4), dim3(TB), 0, stream,
                       h1b, WtP + 512 * 128, bq2, bk2, bv2, bs2, q, kb, vb, skip, N);
    hipLaunchKernelGGL(attn_agg<float>, dim3(gAttn), dim3(TB), 0, stream,
                       q, kb, vb, row_ptr, srcs, skip, x, a, out, N);
}

// Round 3
// 586.797 us; speedup vs baseline: 2.0578x; 1.2747x over previous
//
#include <hip/hip_runtime.h>
#include <hip/hip_bf16.h>
#include <math.h>

#define D 128
#define SCALE 0.25f

typedef __attribute__((ext_vector_type(8))) short bf16x8;
typedef __attribute__((ext_vector_type(4))) float f32x4;

// ---------------------------------------------------------------------------
// edge_index dtype detection (int64 vs int32) — see round 0 notes.
__global__ void detect_i64(const int* __restrict__ ei, int* __restrict__ flag) {
    __shared__ int cnt;
    if (threadIdx.x == 0) cnt = 0;
    __syncthreads();
    int v = ei[2 * threadIdx.x + 1];
    if (v != 0) atomicAdd(&cnt, 1);
    __syncthreads();
    if (threadIdx.x == 0) flag[0] = (cnt == 0) ? 1 : 0;
}

__global__ void zero_ints(int* __restrict__ p, int n) {
    int i = blockIdx.x * blockDim.x + threadIdx.x;
    if (i < n) p[i] = 0;
}

__global__ void count_deg(const int* __restrict__ ei, int E,
                          const int* __restrict__ flag, int* __restrict__ deg) {
    int e = blockIdx.x * blockDim.x + threadIdx.x;
    if (e >= E) return;
    int is64 = flag[0];
    int d = is64 ? ei[2 * E + 2 * e] : ei[E + e];
    atomicAdd(&deg[d], 1);
}

// ---- 3-phase device-wide exclusive scan
__global__ __launch_bounds__(1024) void scan_blocks(const int* __restrict__ deg,
                                                    int* __restrict__ row_ptr,
                                                    int* __restrict__ bsum, int Nn) {
    __shared__ int buf[1024];
    int tid = threadIdx.x;
    int i = blockIdx.x * 1024 + tid;
    int v = (i < Nn) ? deg[i] : 0;
    buf[tid] = v;
    __syncthreads();
    for (int off = 1; off < 1024; off <<= 1) {
        int t = (tid >= off) ? buf[tid - off] : 0;
        __syncthreads();
        buf[tid] += t;
        __syncthreads();
    }
    if (i < Nn) row_ptr[i] = buf[tid] - v;   // block-local exclusive
    if (tid == 1023) bsum[blockIdx.x] = buf[1023];
}

__global__ __launch_bounds__(1024) void scan_bsum(int* __restrict__ bsum,
                                                  int* __restrict__ boff,
                                                  int NB, int* __restrict__ row_ptr, int Nn) {
    __shared__ int buf[1024];
    int tid = threadIdx.x;
    int v = (tid < NB) ? bsum[tid] : 0;
    buf[tid] = v;
    __syncthreads();
    for (int off = 1; off < 1024; off <<= 1) {
        int t = (tid >= off) ? buf[tid - off] : 0;
        __syncthreads();
        buf[tid] += t;
        __syncthreads();
    }
    if (tid < NB) boff[tid] = buf[tid] - v;
    if (tid == 0) row_ptr[Nn] = buf[NB - 1];  // grand total
}

__global__ void add_offsets(int* __restrict__ row_ptr, int* __restrict__ cursor,
                            const int* __restrict__ boff, int Nn) {
    int i = blockIdx.x * blockDim.x + threadIdx.x;
    if (i < Nn) {
        int r = row_ptr[i] + boff[i >> 10];
        row_ptr[i] = r;
        cursor[i] = r;
    }
}

__global__ void scatter_edges(const int* __restrict__ ei, int E,
                              const int* __restrict__ flag,
                              int* __restrict__ cursor, int* __restrict__ srcs) {
    int e = blockIdx.x * blockDim.x + threadIdx.x;
    if (e >= E) return;
    int is64 = flag[0];
    int s = is64 ? ei[2 * e]         : ei[e];
    int d = is64 ? ei[2 * E + 2 * e] : ei[E + e];
    int pos = atomicAdd(&cursor[d], 1);
    srcs[pos] = s;
}

// ---------------------------------------------------------------------------
// Pack 8 fp32 [128,128] weight matrices (k-major) into bf16 col-major
struct PackArgs { const float* w[8]; };

__global__ __launch_bounds__(256) void pack_w(PackArgs pa, __hip_bfloat16* __restrict__ out) {
    int b = blockIdx.x;
    const float* W = pa.w[b];
    __hip_bfloat16* dst = out + (size_t)b * 128 * 128;
    for (int idx = threadIdx.x; idx < 128 * 128; idx += 256) {
        int c = idx & 127, k = idx >> 7;
        dst[(size_t)c * 128 + k] = __float2bfloat16(W[(size_t)k * 128 + c]);
    }
}

__global__ void f32_to_bf16(const float* __restrict__ in, __hip_bfloat16* __restrict__ out, int n4) {
    int i = blockIdx.x * blockDim.x + threadIdx.x;
    if (i >= n4) return;
    float4 v = ((const float4*)in)[i];
    __hip_bfloat162 a, b;
    a.x = __float2bfloat16(v.x); a.y = __float2bfloat16(v.y);
    b.x = __float2bfloat16(v.z); b.y = __float2bfloat16(v.w);
    ((__hip_bfloat162*)out)[2 * i]     = a;
    ((__hip_bfloat162*)out)[2 * i + 1] = b;
}

// ---------------------------------------------------------------------------
// Fused 4-way GEMM, one block = 64 rows x all 512 output cols (cb loop inside).
// A fragments loaded ONCE into registers (32 VGPR), reused across 4 cb.
// q (f32), k/v interleaved into kv[N,256] bf16, skip (f32).
__global__ __launch_bounds__(256) void gemm_mfma(
    const __hip_bfloat16* __restrict__ A,   // [M,128]
    const __hip_bfloat16* __restrict__ Wt,  // [512,128] (col,k)
    const float* __restrict__ bq, const float* __restrict__ bk,
    const float* __restrict__ bv, const float* __restrict__ bs,
    float* __restrict__ qout, __hip_bfloat16* __restrict__ kv,
    float* __restrict__ sout, int M)
{
    const int tid = threadIdx.x;
    const int w = tid >> 6, lane = tid & 63;
    const int wr = w >> 1, wc = w & 1;
    const int rowBase = blockIdx.x * 64 + wr * 32;
    const int l16 = lane & 15;
    const int quad = lane >> 4;

    // A fragments: 2 i-tiles x 4 kb, resident for the whole kernel
    bf16x8 afrag[2][4];
    #pragma unroll
    for (int i = 0; i < 2; ++i) {
        int r = rowBase + i * 16 + l16;
        if (r >= M) r = M - 1;     // row r of D depends only on row r of A
        #pragma unroll
        for (int kb = 0; kb < 4; ++kb)
            afrag[i][kb] = *(const bf16x8*)(A + (size_t)r * D + kb * 32 + quad * 8);
    }

    const float* biases[4] = {bq, bk, bv, bs};

    #pragma unroll
    for (int cb = 0; cb < 4; ++cb) {
        const __hip_bfloat16* Wblk = Wt + (size_t)cb * 128 * 128;
        f32x4 acc[2][4];
        #pragma unroll
        for (int i = 0; i < 2; i++)
            #pragma unroll
            for (int j = 0; j < 4; j++) acc[i][j] = (f32x4){0.f, 0.f, 0.f, 0.f};

        #pragma unroll
        for (int kb = 0; kb < 4; ++kb) {
            const int k0 = kb * 32 + quad * 8;
            #pragma unroll
            for (int j = 0; j < 4; ++j) {
                int c = wc * 64 + j * 16 + l16;
                bf16x8 bfrag = *(const bf16x8*)(Wblk + (size_t)c * D + k0);
                acc[0][j] = __builtin_amdgcn_mfma_f32_16x16x32_bf16(afrag[0][kb], bfrag, acc[0][j], 0, 0, 0);
                acc[1][j] = __builtin_amdgcn_mfma_f32_16x16x32_bf16(afrag[1][kb], bfrag, acc[1][j], 0, 0, 0);
            }
        }

        const float* bias = biases[cb];
        float bcol[4];
        #pragma unroll
        for (int j = 0; j < 4; ++j) bcol[j] = bias[wc * 64 + j * 16 + l16];

        // C/D layout: col = lane&15, row = quad*4 + reg  [m89-verified]
        #pragma unroll
        for (int i = 0; i < 2; ++i) {
            #pragma unroll
            for (int r = 0; r < 4; ++r) {
                int grow = rowBase + i * 16 + quad * 4 + r;
                if (grow >= M) continue;
                #pragma unroll
                for (int j = 0; j < 4; ++j) {
                    int col = wc * 64 + j * 16 + l16;
                    float val = acc[i][j][r] + bcol[j];
                    if (cb == 0)      qout[(size_t)grow * D + col] = val;
                    else if (cb == 1) kv[(size_t)grow * 256 + col] = __float2bfloat16(val);
                    else if (cb == 2) kv[(size_t)grow * 256 + 128 + col] = __float2bfloat16(val);
                    else              sout[(size_t)grow * D + col] = val;
                }
            }
        }
    }
}

// ---------------------------------------------------------------------------
// One wave per dst node, online softmax, 4-edge batches for MLP/ILP.
// Lane l holds dims {2l, 2l+1}; head h = l>>3; dot reduced over 8 lanes.
__device__ inline void store_pair(float* base, int idx, float o0, float o1) {
    ((float2*)base)[idx] = make_float2(o0, o1);
}
__device__ inline void store_pair(__hip_bfloat16* base, int idx, float o0, float o1) {
    __hip_bfloat162 hv;
    hv.x = __float2bfloat16(o0);
    hv.y = __float2bfloat16(o1);
    ((__hip_bfloat162*)base)[idx] = hv;
}

template <typename OutT>
__global__ __launch_bounds__(256) void attn_agg(
    const float* __restrict__ q, const __hip_bfloat16* __restrict__ kv,
    const int* __restrict__ row_ptr, const int* __restrict__ srcs,
    const float* __restrict__ skip, const float* __restrict__ resid,
    const float* __restrict__ a_ptr, OutT* __restrict__ out, int Nn) {
    int n = blockIdx.x * 4 + (threadIdx.x >> 6);
    if (n >= Nn) return;
    int lane = threadIdx.x & 63;
    const float a = a_ptr[0];

    float2 qv = ((const float2*)(q + (size_t)n * D))[lane];
    float m = -INFINITY, s = 0.f, a0 = 0.f, a1 = 0.f;

    int beg = __builtin_amdgcn_readfirstlane(row_ptr[n]);
    int end = __builtin_amdgcn_readfirstlane(row_ptr[n + 1]);
    int j = beg;

    for (; j + 4 <= end; j += 4) {
        int s0 = srcs[j], s1 = srcs[j + 1], s2 = srcs[j + 2], s3 = srcs[j + 3];
        const __hip_bfloat162* r0 = (const __hip_bfloat162*)kv + (size_t)s0 * 128;
        const __hip_bfloat162* r1 = (const __hip_bfloat162*)kv + (size_t)s1 * 128;
        const __hip_bfloat162* r2 = (const __hip_bfloat162*)kv + (size_t)s2 * 128;
        const __hip_bfloat162* r3 = (const __hip_bfloat162*)kv + (size_t)s3 * 128;
        __hip_bfloat162 k0 = r0[lane],      k1 = r1[lane],      k2 = r2[lane],      k3 = r3[lane];
        __hip_bfloat162 v0 = r0[64 + lane], v1 = r1[64 + lane], v2 = r2[64 + lane], v3 = r3[64 + lane];

        float p0 = qv.x * __bfloat162float(k0.x) + qv.y * __bfloat162float(k0.y);
        float p1 = qv.x * __bfloat162float(k1.x) + qv.y * __bfloat162float(k1.y);
        float p2 = qv.x * __bfloat162float(k2.x) + qv.y * __bfloat162float(k2.y);
        float p3 = qv.x * __bfloat162float(k3.x) + qv.y * __bfloat162float(k3.y);
        #pragma unroll
        for (int off = 1; off < 8; off <<= 1) {
            p0 += __shfl_xor(p0, off);
            p1 += __shfl_xor(p1, off);
            p2 += __shfl_xor(p2, off);
            p3 += __shfl_xor(p3, off);
        }
        float sc0 = p0 * SCALE, sc1 = p1 * SCALE, sc2 = p2 * SCALE, sc3 = p3 * SCALE;

        float nm = fmaxf(fmaxf(m, sc0), fmaxf(fmaxf(sc1, sc2), sc3));
        float corr = __expf(m - nm);          // first batch: exp(-inf)=0
        float w0 = __expf(sc0 - nm), w1 = __expf(sc1 - nm);
        float w2 = __expf(sc2 - nm), w3 = __expf(sc3 - nm);
        a0 = a0 * corr + w0 * __bfloat162float(v0.x) + w1 * __bfloat162float(v1.x)
                       + w2 * __bfloat162float(v2.x) + w3 * __bfloat162float(v3.x);
        a1 = a1 * corr + w0 * __bfloat162float(v0.y) + w1 * __bfloat162float(v1.y)
                       + w2 * __bfloat162float(v2.y) + w3 * __bfloat162float(v3.y);
        s = s * corr + (w0 + w1) + (w2 + w3);
        m = nm;
    }

    for (; j < end; ++j) {
        int src = srcs[j];
        const __hip_bfloat162* rr = (const __hip_bfloat162*)kv + (size_t)src * 128;
        __hip_bfloat162 kp = rr[lane];
        __hip_bfloat162 vp = rr[64 + lane];
        float p = qv.x * __bfloat162float(kp.x) + qv.y * __bfloat162float(kp.y);
        p += __shfl_xor(p, 1);
        p += __shfl_xor(p, 2);
        p += __shfl_xor(p, 4);
        float sc = p * SCALE;
        float nm = fmaxf(m, sc);
        float corr = __expf(m - nm);
        float wgt = __expf(sc - nm);
        a0 = a0 * corr + wgt * __bfloat162float(vp.x);
        a1 = a1 * corr + wgt * __bfloat162float(vp.y);
        s = s * corr + wgt;
        m = nm;
    }

    float inv = (end > beg) ? 1.f / s : 0.f;
    float2 sk = ((const float2*)(skip + (size_t)n * D))[lane];
    float o0 = a0 * inv + sk.x;
    float o1 = a1 * inv + sk.y;
    if (resid) {
        float2 rs = ((const float2*)(resid + (size_t)n * D))[lane];
        o0 += rs.x; o1 += rs.y;
    }
    o0 = (o0 >= 0.f) ? o0 : a * o0;
    o1 = (o1 >= 0.f) ? o1 : a * o1;
    store_pair(out, n * (D / 2) + lane, o0, o1);
}

// ---------------------------------------------------------------------------
extern "C" void kernel_launch(void* const* d_in, const int* in_sizes, int n_in,
                              void* d_out, int out_size, void* d_ws, size_t ws_size,
                              hipStream_t stream) {
    const float* x  = (const float*)d_in[0];
    const int*   ei = (const int*)d_in[1];
    const float* a  = (const float*)d_in[2];
    const float* Wq1 = (const float*)d_in[3];  const float* bq1 = (const float*)d_in[4];
    const float* Wk1 = (const float*)d_in[5];  const float* bk1 = (const float*)d_in[6];
    const float* Wv1 = (const float*)d_in[7];  const float* bv1 = (const float*)d_in[8];
    const float* Ws1 = (const float*)d_in[9];  const float* bs1 = (const float*)d_in[10];
    const float* Wq2 = (const float*)d_in[11]; const float* bq2 = (const float*)d_in[12];
    const float* Wk2 = (const float*)d_in[13]; const float* bk2 = (const float*)d_in[14];
    const float* Wv2 = (const float*)d_in[15]; const float* bv2 = (const float*)d_in[16];
    const float* Ws2 = (const float*)d_in[17]; const float* bs2 = (const float*)d_in[18];

    const int N = in_sizes[0] / D;        // 100000
    const int E = in_sizes[1] / 2;        // 1000000
    const size_t NF = (size_t)N * D;

    char* wp = (char*)d_ws;
    __hip_bfloat16* xb  = (__hip_bfloat16*)wp; wp += NF * 2;
    __hip_bfloat16* h1b = (__hip_bfloat16*)wp; wp += NF * 2;
    float* q            = (float*)wp;          wp += NF * 4;
    __hip_bfloat16* kv  = (__hip_bfloat16*)wp; wp += NF * 4;   // [N,256] interleaved k|v
    __hip_bfloat16* WtP = (__hip_bfloat16*)wp; wp += 2 * 512 * 128 * 2;
    int* flag    = (int*)wp;  wp += 64;
    int* deg     = (int*)wp;  wp += (size_t)N * 4;
    int* row_ptr = (int*)wp;  wp += (size_t)(N + 64) * 4;
    int* cursor  = (int*)wp;  wp += (size_t)N * 4;
    int* bsum    = (int*)wp;  wp += 1024 * 4;
    int* boff    = (int*)wp;  wp += 1024 * 4;
    int* srcs    = (int*)wp;  wp += (size_t)E * 4;
    float* skip  = (float*)d_out;
    float* out   = (float*)d_out;

    const int TB = 256;
    int gN = (N + TB - 1) / TB;
    int gE = (E + TB - 1) / TB;
    int NB = (N + 1023) / 1024;
    int gGemm = (N + 63) / 64;
    int gAttn = (N + 3) / 4;
    int gCvt  = ((int)(NF / 4) + TB - 1) / TB;

    // ---- CSR build ----
    hipLaunchKernelGGL(detect_i64, dim3(1), dim3(1024), 0, stream, ei, flag);
    hipLaunchKernelGGL(zero_ints, dim3(gN), dim3(TB), 0, stream, deg, N);
    hipLaunchKernelGGL(count_deg, dim3(gE), dim3(TB), 0, stream, ei, E, flag, deg);
    hipLaunchKernelGGL(scan_blocks, dim3(NB), dim3(1024), 0, stream, deg, row_ptr, bsum, N);
    hipLaunchKernelGGL(scan_bsum, dim3(1), dim3(1024), 0, stream, bsum, boff, NB, row_ptr, N);
    hipLaunchKernelGGL(add_offsets, dim3(gN), dim3(TB), 0, stream, row_ptr, cursor, boff, N);
    hipLaunchKernelGGL(scatter_edges, dim3(gE), dim3(TB), 0, stream, ei, E, flag, cursor, srcs);

    // ---- weight pack + input convert ----
    PackArgs pa;
    pa.w[0] = Wq1; pa.w[1] = Wk1; pa.w[2] = Wv1; pa.w[3] = Ws1;
    pa.w[4] = Wq2; pa.w[5] = Wk2; pa.w[6] = Wv2; pa.w[7] = Ws2;
    hipLaunchKernelGGL(pack_w, dim3(8), dim3(TB), 0, stream, pa, WtP);
    hipLaunchKernelGGL(f32_to_bf16, dim3(gCvt), dim3(TB), 0, stream, x, xb, (int)(NF / 4));

    // ---- layer 1 ----
    hipLaunchKernelGGL(gemm_mfma, dim3(gGemm), dim3(TB), 0, stream,
                       xb, WtP, bq1, bk1, bv1, bs1, q, kv, skip, N);
    hipLaunchKernelGGL(attn_agg<__hip_bfloat16>, dim3(gAttn), dim3(TB), 0, stream,
                       q, kv, row_ptr, srcs, skip, (const float*)nullptr, a, h1b, N);

    // ---- layer 2 ----
    hipLaunchKernelGGL(gemm_mfma, dim3(gGemm), dim3(TB), 0, stream,
                       h1b, WtP + 512 * 128, bq2, bk2, bv2, bs2, q, kv, skip, N);
    hipLaunchKernelGGL(attn_agg<float>, dim3(gAttn), dim3(TB), 0, stream,
                       q, kv, row_ptr, srcs, skip, x, a, out, N);
}